// Round 9
// baseline (112.713 us; speedup 1.0000x reference)
//
#include <hip/hip_runtime.h>
#include <stdint.h>

#define TPB 256
#define FDIM 512
#define HD 32
#define AD 8
#define RPB 256            // rows per block
#define RT 32              // rows per staging tile (full K each)
#define NRT (RPB / RT)     // 8 tiles
#define H1P 40             // h1 pitch in bf16 units (80 B, 16B-aligned)

typedef __bf16 bf16x8 __attribute__((ext_vector_type(8)));
typedef float f32x4 __attribute__((ext_vector_type(4)));
typedef uint32_t u32x4 __attribute__((ext_vector_type(4)));

// Barrier publishing LDS writes WITHOUT draining vmcnt: prefetch global loads
// stay in flight across it (round-8 verified safe & race-free).
#define BARRIER_LGKM() asm volatile("s_waitcnt lgkmcnt(0)\n\ts_barrier" ::: "memory")

__device__ __forceinline__ uint32_t rotl32(uint32_t x, int r) {
  return (x << r) | (x >> (32 - r));
}

// Threefry-2x32 with key (0, 42) == jax.random.key(42); 20 rounds.
__device__ __forceinline__ void tf2x32_key42(uint32_t& x0, uint32_t& x1) {
  const uint32_t ks0 = 0u, ks1 = 42u, ks2 = 0x1BD11BDAu ^ 0u ^ 42u;
  x0 += ks0; x1 += ks1;
#define TFR(r) { x0 += x1; x1 = rotl32(x1, (r)); x1 ^= x0; }
  TFR(13) TFR(15) TFR(26) TFR(6)
  x0 += ks1; x1 += ks2 + 1u;
  TFR(17) TFR(29) TFR(16) TFR(24)
  x0 += ks2; x1 += ks0 + 2u;
  TFR(13) TFR(15) TFR(26) TFR(6)
  x0 += ks0; x1 += ks1 + 3u;
  TFR(17) TFR(29) TFR(16) TFR(24)
  x0 += ks1; x1 += ks2 + 4u;
  TFR(13) TFR(15) TFR(26) TFR(6)
  x0 += ks2; x1 += ks0 + 5u;
#undef TFR
}

// jax.random.normal f32 from raw bits (XLA ErfInv32 / Giles polynomial).
__device__ __forceinline__ float jax_normal_from_bits(uint32_t bits) {
  float u = __uint_as_float((bits >> 9) | 0x3f800000u) - 1.0f;
  const float lo = -0.99999994f;           // nextafter(-1, 0)
  float v = fmaxf(lo, fmaf(u, 2.0f, lo));
  float w = -log1pf(-v * v);
  float p;
  if (w < 5.0f) {
    w -= 2.5f;
    p = 2.81022636e-08f;
    p = fmaf(p, w, 3.43273939e-07f);
    p = fmaf(p, w, -3.5233877e-06f);
    p = fmaf(p, w, -4.39150654e-06f);
    p = fmaf(p, w, 0.00021858087f);
    p = fmaf(p, w, -0.00125372503f);
    p = fmaf(p, w, -0.00417768164f);
    p = fmaf(p, w, 0.246640727f);
    p = fmaf(p, w, 1.50140941f);
  } else {
    w = sqrtf(w) - 3.0f;
    p = -0.000200214257f;
    p = fmaf(p, w, 0.000100950558f);
    p = fmaf(p, w, 0.00134934322f);
    p = fmaf(p, w, -0.00367342844f);
    p = fmaf(p, w, 0.00573950773f);
    p = fmaf(p, w, -0.0076224613f);
    p = fmaf(p, w, 0.00943887047f);
    p = fmaf(p, w, 1.00167406f);
    p = fmaf(p, w, 2.83297682f);
  }
  return 1.41421356f * (p * v);
}

// pack two f32 -> one u32 of two bf16 (RNE)
__device__ __forceinline__ uint32_t bf2(float a, float b) {
  uint32_t ua = __float_as_uint(a);
  uint32_t ub = __float_as_uint(b);
  ua = (ua + 0x7fffu + ((ua >> 16) & 1u)) >> 16;
  ub = (ub + 0x7fffu + ((ub >> 16) & 1u)) >> 16;
  return ua | (ub << 16);
}

__device__ __forceinline__ uint16_t bf1(float x) {
  uint32_t u = __float_as_uint(x);
  return (uint16_t)((u + 0x7fffu + ((u >> 16) & 1u)) >> 16);
}

__device__ __forceinline__ bf16x8 pack8(float4 a, float4 b) {
  u32x4 r;
  r.x = bf2(a.x, a.y);
  r.y = bf2(a.z, a.w);
  r.z = bf2(b.x, b.y);
  r.w = bf2(b.z, b.w);
  return __builtin_bit_cast(bf16x8, r);
}

// Row-tiled layer 1: per iteration stage 32 rows x 512 cols of X (fully
// SEQUENTIAL 64KB global read), consume complete K per tile. Each wave owns
// quadrant (m = wid>>1, nt = wid&1); W1 B-frags live in VGPRs (loaded once).
// h1 accumulates in a bf16 LDS buffer; scalar tail per row unchanged.
__global__ __launch_bounds__(TPB, 2) void naf_fused(
    const float* __restrict__ X, const float* __restrict__ RL,
    const float* __restrict__ act,
    const float* __restrict__ W1, const float* __restrict__ b1,
    const float* __restrict__ W2, const float* __restrict__ b2,
    const float* __restrict__ Wv, const float* __restrict__ bv,
    const float* __restrict__ Wmu, const float* __restrict__ bmu,
    const float* __restrict__ WL, const float* __restrict__ bL,
    float* __restrict__ out, int N) {
  __shared__ __align__(16) char sX[RT * 1024];       // 32 KB: [32][512] bf16, swizzled
  __shared__ __align__(16) uint16_t sh1[RPB * H1P];  // 20 KB: h1 bf16, pitch 40
  __shared__ float sW2[HD * HD];                     // 4 KB
  __shared__ float sWmu[HD * AD];                    // [k][a]
  __shared__ float sWLd[HD * AD];                    // diag cols of WL, [k][a]
  __shared__ float sWv[HD];
  __shared__ float sb2[HD], sbmu[AD], sbLd[AD];
  __shared__ float sbv;

  const int tid  = threadIdx.x;
  const int lane = tid & 63;
  const int wid  = tid >> 6;
  const int llo  = lane & 15;   // A row / B col within 16-tile
  const int lhi  = lane >> 4;   // k-group (x8)
  const int m    = wid >> 1;    // wave's m-tile (0..1)
  const int nt   = wid & 1;     // wave's col-half (0..1)
  const int R0   = blockIdx.x * RPB;

  const float4* Xv = reinterpret_cast<const float4*>(X);  // row = 128 float4

#define LOADX(rg)                                                   \
  {                                                                 \
    _Pragma("unroll")                                               \
    for (int it = 0; it < 16; ++it) {                               \
      const int g = it * TPB + tid;      /* 0..4095, sequential */  \
      const int rl = (rg) * RT + (g >> 7);                          \
      int r = R0 + rl;                                              \
      r = r < N ? r : (N - 1);                                      \
      xreg[it] = Xv[(size_t)r * (FDIM / 4) + (g & 127)];            \
    }                                                               \
  }

  // ---- issue X tile 0 immediately (HBM latency starts now) ----
  float4 xreg[16];
  LOADX(0)

  // ---- W1 B-frags into VGPRs, once (L2-hot across blocks) ----
  bf16x8 bfrag[16];
  {
    const float* wcol = W1 + nt * 16 + llo;
#pragma unroll
    for (int kc = 0; kc < 16; ++kc) {
      const float* wp = wcol + (size_t)(kc * 32 + lhi * 8) * HD;
      float4 v0, v1;
      v0.x = wp[0 * HD]; v0.y = wp[1 * HD]; v0.z = wp[2 * HD]; v0.w = wp[3 * HD];
      v1.x = wp[4 * HD]; v1.y = wp[5 * HD]; v1.z = wp[6 * HD]; v1.w = wp[7 * HD];
      bfrag[kc] = pack8(v0, v1);
    }
  }
  const float b1c = b1[nt * 16 + llo];  // wave's bias column

  // ---- stage small weights (read only by the tail) ----
  for (int i = tid; i < HD * HD; i += TPB) sW2[i] = W2[i];
  if (tid < 256) {
    sWmu[tid] = Wmu[tid];
    const int k = tid >> 3, a = tid & 7;
    sWLd[tid] = WL[k * 36 + ((a * a + 3 * a) >> 1)];  // tril diag idx a(a+3)/2
  }
  if (tid < HD) { sWv[tid] = Wv[tid]; sb2[tid] = b2[tid]; }
  if (tid < AD) { sbmu[tid] = bmu[tid]; sbLd[tid] = bL[(tid * tid + 3 * tid) >> 1]; }
  if (tid == 0) sbv = bv[0];

  // ---- row-group loop: 8 x {stage 32 rows, full-K MFMA, h1 scatter} ----
#pragma unroll 1
  for (int rg = 0; rg < NRT; ++rg) {
    // write current tile (regs -> bf16 LDS, XOR-swizzled); compiler inserts
    // the vmcnt waits for xreg here. WAR-safe: prior bar2 drained readers.
#pragma unroll
    for (int it = 0; it < 16; ++it) {
      const int g = it * TPB + tid;
      const int row = g >> 7;          // 0..31
      const int col4 = g & 127;        // float4 col
      uint2 pkd = make_uint2(bf2(xreg[it].x, xreg[it].y),
                             bf2(xreg[it].z, xreg[it].w));
      const int boff = (col4 * 8) ^ ((row & 7) << 4);
      *reinterpret_cast<uint2*>(sX + row * 1024 + boff) = pkd;
    }
    if (rg + 1 < NRT) LOADX(rg + 1)   // next tile flies across barriers+MFMA
    BARRIER_LGKM();

    // full-K MFMA for this wave's quadrant
    f32x4 acc = (f32x4){0.0f, 0.0f, 0.0f, 0.0f};
    const int arow = m * 16 + llo;
    const char* abase = sX + arow * 1024;
    const int aswz = (llo & 7) << 4;
#pragma unroll
    for (int kc = 0; kc < 16; ++kc) {
      bf16x8 afrag = *reinterpret_cast<const bf16x8*>(
          abase + ((kc * 64 + lhi * 16) ^ aswz));
      acc = __builtin_amdgcn_mfma_f32_16x16x32_bf16(afrag, bfrag[kc], acc, 0, 0, 0);
    }

    // h1 scatter: C-layout col=llo(+nt*16), row=lhi*4+i; bias+ReLU, bf16
#pragma unroll
    for (int i = 0; i < 4; ++i) {
      const int rowl = rg * RT + m * 16 + lhi * 4 + i;
      sh1[rowl * H1P + nt * 16 + llo] = bf1(fmaxf(acc[i] + b1c, 0.0f));
    }
    BARRIER_LGKM();  // readers done; next stage may overwrite sX
  }

  // ---- finalize: thread t owns row R0 + t (h1 all published by last bar) ----
  const int row = R0 + tid;
  if (row >= N) return;  // no barriers below

  float h1v[HD];
  {
    const uint16_t* hp = &sh1[tid * H1P];
#pragma unroll
    for (int q = 0; q < 4; ++q) {
      u32x4 u = *reinterpret_cast<const u32x4*>(hp + q * 8);
#pragma unroll
      for (int j = 0; j < 4; ++j) {
        const uint32_t wv = u[j];
        h1v[q * 8 + 2 * j]     = __uint_as_float(wv << 16);
        h1v[q * 8 + 2 * j + 1] = __uint_as_float(wv & 0xffff0000u);
      }
    }
  }

  // layer 2: 32x32
  float acc2[HD];
#pragma unroll
  for (int c = 0; c < HD; ++c) acc2[c] = 0.0f;
  {
    const float4* w2v = reinterpret_cast<const float4*>(sW2);
#pragma unroll 4
    for (int k = 0; k < HD; ++k) {
      const float hk = h1v[k];
#pragma unroll
      for (int q = 0; q < HD / 4; ++q) {
        float4 wv = w2v[k * (HD / 4) + q];
        acc2[4 * q + 0] = fmaf(hk, wv.x, acc2[4 * q + 0]);
        acc2[4 * q + 1] = fmaf(hk, wv.y, acc2[4 * q + 1]);
        acc2[4 * q + 2] = fmaf(hk, wv.z, acc2[4 * q + 2]);
        acc2[4 * q + 3] = fmaf(hk, wv.w, acc2[4 * q + 3]);
      }
    }
  }
  float h2[HD];
#pragma unroll
  for (int c = 0; c < HD; ++c) h2[c] = fmaxf(acc2[c] + sb2[c], 0.0f);

  // heads: value, mu (8), L-diagonal (8)
  float vacc = 0.0f;
  float mua[AD], dva[AD];
#pragma unroll
  for (int a = 0; a < AD; ++a) { mua[a] = 0.0f; dva[a] = 0.0f; }
  {
    const float4* wmu4 = reinterpret_cast<const float4*>(sWmu);
    const float4* wld4 = reinterpret_cast<const float4*>(sWLd);
#pragma unroll 4
    for (int k = 0; k < HD; ++k) {
      const float hk = h2[k];
      vacc = fmaf(hk, sWv[k], vacc);
      float4 m0 = wmu4[2 * k], m1 = wmu4[2 * k + 1];
      float4 l0 = wld4[2 * k], l1 = wld4[2 * k + 1];
      mua[0] = fmaf(hk, m0.x, mua[0]); mua[1] = fmaf(hk, m0.y, mua[1]);
      mua[2] = fmaf(hk, m0.z, mua[2]); mua[3] = fmaf(hk, m0.w, mua[3]);
      mua[4] = fmaf(hk, m1.x, mua[4]); mua[5] = fmaf(hk, m1.y, mua[5]);
      mua[6] = fmaf(hk, m1.z, mua[6]); mua[7] = fmaf(hk, m1.w, mua[7]);
      dva[0] = fmaf(hk, l0.x, dva[0]); dva[1] = fmaf(hk, l0.y, dva[1]);
      dva[2] = fmaf(hk, l0.z, dva[2]); dva[3] = fmaf(hk, l0.w, dva[3]);
      dva[4] = fmaf(hk, l1.x, dva[4]); dva[5] = fmaf(hk, l1.y, dva[5]);
      dva[6] = fmaf(hk, l1.z, dva[6]); dva[7] = fmaf(hk, l1.w, dva[7]);
    }
  }
  vacc += sbv;

  // diagonal NAF closed form + Threefry sampling (partitionable)
  const float actn = act[row];
  const float rl_mask = RL[row];
  float adv = 0.0f;
  float smp[AD];
#pragma unroll
  for (int a = 0; a < AD; ++a) {
    const float mu = tanhf(mua[a] + sbmu[a]);
    const float dd = tanhf(dva[a] + sbLd[a]);
    const float ld = expf(dd);     // L diagonal; P_aa = ld^2; Lc_aa = 1/ld
    const float am = actn - mu;
    adv = fmaf(am * am, ld * ld, adv);
    const uint32_t e = (uint32_t)row * AD + (uint32_t)a;
    uint32_t x0 = 0u;
    uint32_t x1 = e;
    tf2x32_key42(x0, x1);
    const float z = jax_normal_from_bits(x0 ^ x1);
    float s = fmaf(z, 1.0f / ld, mu);
    s = fminf(fmaxf(s, -1.0f), 1.0f) * rl_mask;
    smp[a] = s;
  }
  const float q = fmaf(-0.5f, adv, vacc);

  float4* so = reinterpret_cast<float4*>(out) + (size_t)row * 2;
  so[0] = make_float4(smp[0], smp[1], smp[2], smp[3]);
  so[1] = make_float4(smp[4], smp[5], smp[6], smp[7]);
  out[(size_t)N * AD + row] = q;                  // Q
  out[(size_t)N * AD + (size_t)N + row] = vacc;   // value
#undef LOADX
}

extern "C" void kernel_launch(void* const* d_in, const int* in_sizes, int n_in,
                              void* d_out, int out_size, void* d_ws, size_t ws_size,
                              hipStream_t stream) {
  const float* X   = (const float*)d_in[0];
  const float* RL  = (const float*)d_in[1];
  const float* act = (const float*)d_in[2];
  const float* W1  = (const float*)d_in[3];
  const float* b1  = (const float*)d_in[4];
  const float* W2  = (const float*)d_in[5];
  const float* b2  = (const float*)d_in[6];
  const float* Wv  = (const float*)d_in[7];
  const float* bv  = (const float*)d_in[8];
  const float* Wmu = (const float*)d_in[9];
  const float* bmu = (const float*)d_in[10];
  const float* WL  = (const float*)d_in[11];
  const float* bL  = (const float*)d_in[12];
  const int N = in_sizes[1];  // RL_indice length
  const int blocks = (N + RPB - 1) / RPB;
  hipLaunchKernelGGL(naf_fused, dim3(blocks), dim3(TPB), 0, stream,
                     X, RL, act, W1, b1, W2, b2, Wv, bv, Wmu, bmu, WL, bL,
                     (float*)d_out, N);
}